// Round 3
// baseline (745.722 us; speedup 1.0000x reference)
//
#include <hip/hip_runtime.h>

#define NN 2048
#define KK 20
#define BB 16
#define ROWS (BB * NN)
#define T0F 1.8f      // candidate prefilter threshold (exact fallback below)
#define CAP 128       // candidate capacity per row (count ~74 +/- 8.4; P(outside)<1e-7)
#define CSLOT 64      // incoming-list slots per column (in-degree ~Poisson(20))

__device__ __forceinline__ float wred(float x) {
#pragma unroll
    for (int s = 32; s; s >>= 1) x += __shfl_xor(x, s);
    return x;
}

// ---------------------------------------------------------------------------
// Kernel 1: per-row exact top-K. 2 rows per wave (ILP on the serial bisection
// chain). Pure: writes sel_idx/sel_val/rowsum only — no atomics, no scatter.
// Fast path: compact keys >= T0F into LDS, bisect threshold over <=128 cands.
// Fallback (statistically ~never, exact incl. lax.top_k tie semantics):
// full-array bisection with per-iteration reload (keeps VGPR low).
// ---------------------------------------------------------------------------
__global__ __launch_bounds__(256) void topk_kernel(
    const float* __restrict__ A, const float* __restrict__ noise,
    int* __restrict__ sel_idx, float* __restrict__ sel_val,
    float* __restrict__ rowsum)
{
    __shared__ float cand_key[8][CAP];
    __shared__ int   cand_idx[8][CAP];
    __shared__ int   tie_buf[4][64];
    __shared__ int   tie_n[4];

    const int lane = threadIdx.x & 63;
    const int wv   = threadIdx.x >> 6;
    const int row0 = blockIdx.x * 8 + wv * 2;
    const unsigned long long ltm = (1ull << lane) - 1ull;

    const float* Ap[2] = { A + (size_t)row0 * NN, A + (size_t)(row0 + 1) * NN };
    const float* Np[2] = { noise + (size_t)row0 * NN, noise + (size_t)(row0 + 1) * NN };

    // ---- Phase 1: load, dope, compact candidates into LDS ----------------
    int cnt[2] = {0, 0};
#pragma unroll
    for (int c = 0; c < 8; ++c) {
#pragma unroll
        for (int rr = 0; rr < 2; ++rr) {
            float4 a4 = *(const float4*)(Ap[rr] + c * 256 + lane * 4);
            float4 n4 = *(const float4*)(Np[rr] + c * 256 + lane * 4);
            float kk4[4] = { fmaxf(a4.x, 0.f) + n4.x * 1e-4f,
                             fmaxf(a4.y, 0.f) + n4.y * 1e-4f,
                             fmaxf(a4.z, 0.f) + n4.z * 1e-4f,
                             fmaxf(a4.w, 0.f) + n4.w * 1e-4f };
#pragma unroll
            for (int e = 0; e < 4; ++e) {
                bool p = kk4[e] >= T0F;
                unsigned long long m = __ballot(p);
                if (p) {
                    int pos = cnt[rr] + __popcll(m & ltm);
                    if (pos < CAP) {
                        cand_key[wv * 2 + rr][pos] = kk4[e];
                        cand_idx[wv * 2 + rr][pos] = c * 256 + lane * 4 + e;
                    }
                }
                cnt[rr] += __popcll(m);
            }
        }
    }

    // ---- Phase 2: dual interleaved bisection over candidates -------------
    float c0[2], c1[2];
#pragma unroll
    for (int rr = 0; rr < 2; ++rr) {
        c0[rr] = (lane      < cnt[rr] && lane      < CAP) ? cand_key[wv*2+rr][lane]      : -1.f;
        c1[rr] = (lane + 64 < cnt[rr] && lane + 64 < CAP) ? cand_key[wv*2+rr][lane + 64] : -1.f;
    }
    unsigned lo[2], hi[2], tb[2] = {0, 0};
    int act[2], ex[2] = {0, 0};
#pragma unroll
    for (int rr = 0; rr < 2; ++rr) {
        act[rr] = (cnt[rr] > KK && cnt[rr] <= CAP);
        lo[rr] = __float_as_uint(T0F);            // count(>=T0F) = cnt > K
        float mx = fmaxf(c0[rr], c1[rr]);
#pragma unroll
        for (int s = 32; s; s >>= 1) mx = fmaxf(mx, __shfl_xor(mx, s));
        hi[rr] = __float_as_uint(fmaxf(mx, T0F)) + 1u;   // count(>=f(hi)) = 0 < K
    }
    while (act[0] | act[1]) {
#pragma unroll
        for (int rr = 0; rr < 2; ++rr) {
            if (act[rr]) {
                unsigned mid = (lo[rr] + hi[rr]) >> 1;
                float tm = __uint_as_float(mid);
                int c = __popcll(__ballot(c0[rr] >= tm)) +
                        __popcll(__ballot(c1[rr] >= tm));
                if (c == KK) { tb[rr] = mid; ex[rr] = 1; act[rr] = 0; }
                else {
                    if (c > KK) lo[rr] = mid; else hi[rr] = mid;
                    if (hi[rr] - lo[rr] <= 1u) act[rr] = 0;
                }
            }
        }
    }

    // ---- Emission --------------------------------------------------------
#pragma unroll
    for (int rr = 0; rr < 2; ++rr) {
        const int row = row0 + rr;
        int*   si = sel_idx + (size_t)row * KK;
        float* sv = sel_val + (size_t)row * KK;
        float acc = 0.f;
        if (cnt[rr] == KK) {
            if (lane < KK) {
                int idx = cand_idx[wv * 2 + rr][lane];
                float v = fmaxf(Ap[rr][idx], 0.f);
                si[lane] = idx; sv[lane] = v; acc = v;
            }
            float rs = wred(acc);
            if (lane == 0) rowsum[row] = rs;
        } else if (ex[rr]) {
            float t = __uint_as_float(tb[rr]);
            bool p = c0[rr] >= t;
            unsigned long long m = __ballot(p);
            if (p) {
                int pos = __popcll(m & ltm);
                int idx = cand_idx[wv * 2 + rr][lane];
                float v = fmaxf(Ap[rr][idx], 0.f);
                si[pos] = idx; sv[pos] = v; acc += v;
            }
            int run = __popcll(m);
            p = c1[rr] >= t;
            m = __ballot(p);
            if (p) {
                int pos = run + __popcll(m & ltm);
                int idx = cand_idx[wv * 2 + rr][lane + 64];
                float v = fmaxf(Ap[rr][idx], 0.f);
                si[pos] = idx; sv[pos] = v; acc += v;
            }
            float rs = wred(acc);
            if (lane == 0) rowsum[row] = rs;
        } else {
            // ---- exact fallback (reload-based; statistically ~never) -----
            unsigned flo = 0u, fhi = 0x7F800000u, ftb = 0u;
            int fex = 0;
            while (fhi - flo > 1u) {
                unsigned mid = (flo + fhi) >> 1;
                float tm = __uint_as_float(mid);
                int c = 0;
                for (int j = 0; j < 32; ++j) {
                    int idx = j * 64 + lane;
                    float k = fmaxf(Ap[rr][idx], 0.f) + Np[rr][idx] * 1e-4f;
                    c += __popcll(__ballot(k >= tm));
                }
                if (c == KK) { ftb = mid; fex = 1; break; }
                if (c > KK) flo = mid; else fhi = mid;
            }
            if (fex) {
                float t = __uint_as_float(ftb);
                int run = 0;
                for (int j = 0; j < 32; ++j) {
                    int idx = j * 64 + lane;
                    float v = fmaxf(Ap[rr][idx], 0.f);
                    bool p = (v + Np[rr][idx] * 1e-4f) >= t;
                    unsigned long long m = __ballot(p);
                    if (p) {
                        int pos = run + __popcll(m & ltm);
                        si[pos] = idx; sv[pos] = v; acc += v;
                    }
                    run += __popcll(m);
                }
                float rs = wred(acc);
                if (lane == 0) rowsum[row] = rs;
            } else {
                // exact tie at the K boundary: strictly-greater first, then
                // fill ascending-index among ties (lax.top_k semantics).
                float t1 = __uint_as_float(flo);
                int run = 0;
                for (int j = 0; j < 32; ++j) {
                    int idx = j * 64 + lane;
                    float v = fmaxf(Ap[rr][idx], 0.f);
                    bool p = (v + Np[rr][idx] * 1e-4f) > t1;
                    unsigned long long m = __ballot(p);
                    if (p) {
                        int pos = run + __popcll(m & ltm);
                        si[pos] = idx; sv[pos] = v; acc += v;
                    }
                    run += __popcll(m);
                }
                if (lane == 0) tie_n[wv] = 0;
                for (int j = 0; j < 32; ++j) {
                    int idx = j * 64 + lane;
                    float k = fmaxf(Ap[rr][idx], 0.f) + Np[rr][idx] * 1e-4f;
                    if (k == t1) {
                        int p = atomicAdd(&tie_n[wv], 1);
                        if (p < 64) tie_buf[wv][p] = idx;
                    }
                }
                float rs = wred(acc);
                if (lane == 0) {
                    int n = tie_n[wv]; if (n > 64) n = 64;
                    int need = KK - run;
                    float extra = 0.f;
                    for (int s = 0; s < need; ++s) {
                        int bq = 0, bidx = 0x7fffffff;
                        for (int q = 0; q < n; ++q)
                            if (tie_buf[wv][q] < bidx) { bidx = tie_buf[wv][q]; bq = q; }
                        tie_buf[wv][bq] = 0x7fffffff;
                        float v = fmaxf(Ap[rr][bidx], 0.f);
                        si[run + s] = bidx; sv[run + s] = v; extra += v;
                    }
                    rowsum[row] = rs + extra;
                }
            }
        }
    }
}

// ---------------------------------------------------------------------------
// Kernel 2a: column sums (wide, latency-parallel atomics).
// ---------------------------------------------------------------------------
__global__ __launch_bounds__(256) void colsum_kernel(
    const int* __restrict__ sel_idx, const float* __restrict__ sel_val,
    float* __restrict__ colsum)
{
    int t = blockIdx.x * 256 + threadIdx.x;      // 0 .. ROWS*KK-1
    int r = t / KK;
    int cb = r & ~(NN - 1);
    atomicAdd(&colsum[cb + sel_idx[t]], sel_val[t]);
}

// ---------------------------------------------------------------------------
// Kernel 2b: dinv = (1 + 0.5*(rowsum + colsum))^-1/2 and diag2 = dinv^2.
// ---------------------------------------------------------------------------
__global__ __launch_bounds__(256) void dinv_kernel(
    const float* __restrict__ rowsum, const float* __restrict__ colsum,
    float* __restrict__ dinv, float* __restrict__ diag2)
{
    int r = blockIdx.x * 256 + threadIdx.x;
    float d = 1.0f + 0.5f * (rowsum[r] + colsum[r]);   // d >= 1 always
    float dv = 1.0f / sqrtf(d);
    dinv[r] = dv;
    diag2[r] = dv * dv;
}

// ---------------------------------------------------------------------------
// Kernel 2c: precompute final contribution values 0.5*v*di*dj (coalesced
// store) and build per-column incoming lists as packed (srow<<5 | k).
// ---------------------------------------------------------------------------
__global__ __launch_bounds__(256) void edge_kernel(
    const int* __restrict__ sel_idx, const float* __restrict__ sel_val,
    const float* __restrict__ dinv, float* __restrict__ out_val,
    int* __restrict__ col_cnt, unsigned short* __restrict__ col_pack)
{
    int t = blockIdx.x * 256 + threadIdx.x;      // 0 .. ROWS*KK-1
    int r = t / KK;
    int k = t - r * KK;
    int cb = r & ~(NN - 1);
    int j = sel_idx[t];
    float c = 0.5f * sel_val[t] * dinv[r] * dinv[cb + j];
    out_val[t] = c;
    int s = atomicAdd(&col_cnt[cb + j], 1);
    if (s < CSLOT)
        col_pack[(size_t)(cb + j) * CSLOT + s] =
            (unsigned short)(((r & (NN - 1)) << 5) | k);
}

// ---------------------------------------------------------------------------
// Kernel 3: one block per output row. Zero 8KB LDS row, add diag + outgoing
// (direct) + incoming (one gather hop from L2-hot out_val), stream out.
// ---------------------------------------------------------------------------
__global__ __launch_bounds__(256) void dense_row_kernel(
    const int* __restrict__ sel_idx, const float* __restrict__ out_val,
    const int* __restrict__ col_cnt, const unsigned short* __restrict__ col_pack,
    const float* __restrict__ diag2, float* __restrict__ out)
{
    __shared__ float rowbuf[NN];
    const int r  = blockIdx.x;                   // 0 .. ROWS-1
    const int i  = r & (NN - 1);
    const int cb = r & ~(NN - 1);
    const int t  = threadIdx.x;

    float4 z = {0.f, 0.f, 0.f, 0.f};
    *(float4*)(rowbuf + t * 4) = z;
    *(float4*)(rowbuf + 1024 + t * 4) = z;
    __syncthreads();

    if (t < KK)
        atomicAdd(&rowbuf[sel_idx[(size_t)r * KK + t]],
                  out_val[(size_t)r * KK + t]);
    int cnt = col_cnt[r]; if (cnt > CSLOT) cnt = CSLOT;
    if (t < cnt) {
        unsigned pk = col_pack[(size_t)r * CSLOT + t];
        int srow = pk >> 5, k = pk & 31;
        atomicAdd(&rowbuf[srow], out_val[(size_t)(cb + srow) * KK + k]);
    }
    if (t == 0) atomicAdd(&rowbuf[i], diag2[r]);
    __syncthreads();

    size_t base = (size_t)r * NN;
    *(float4*)(out + base + t * 4) = *(const float4*)(rowbuf + t * 4);
    *(float4*)(out + base + 1024 + t * 4) = *(const float4*)(rowbuf + 1024 + t * 4);
}

// ---------------------------------------------------------------------------
extern "C" void kernel_launch(void* const* d_in, const int* in_sizes, int n_in,
                              void* d_out, int out_size, void* d_ws, size_t ws_size,
                              hipStream_t stream)
{
    const float* A     = (const float*)d_in[0];
    const float* noise = (const float*)d_in[1];
    float* out = (float*)d_out;
    char*  ws  = (char*)d_ws;

    // workspace layout (~12.5 MB)
    size_t off = 0;
    int*   sel_idx = (int*)(ws + off);             off += (size_t)ROWS * KK * 4;
    float* sel_val = (float*)(ws + off);           off += (size_t)ROWS * KK * 4;
    float* out_val = (float*)(ws + off);           off += (size_t)ROWS * KK * 4;
    unsigned short* col_pack = (unsigned short*)(ws + off); off += (size_t)ROWS * CSLOT * 2;
    float* colsum  = (float*)(ws + off);           off += (size_t)ROWS * 4;
    int*   col_cnt = (int*)(ws + off);             off += (size_t)ROWS * 4;
    float* rowsum  = (float*)(ws + off);           off += (size_t)ROWS * 4;
    float* dinv    = (float*)(ws + off);           off += (size_t)ROWS * 4;
    float* diag2   = (float*)(ws + off);           off += (size_t)ROWS * 4;

    hipMemsetAsync(colsum, 0, (size_t)ROWS * 8, stream);  // colsum + col_cnt

    topk_kernel<<<ROWS / 8, 256, 0, stream>>>(A, noise, sel_idx, sel_val, rowsum);
    colsum_kernel<<<ROWS * KK / 256, 256, 0, stream>>>(sel_idx, sel_val, colsum);
    dinv_kernel<<<ROWS / 256, 256, 0, stream>>>(rowsum, colsum, dinv, diag2);
    edge_kernel<<<ROWS * KK / 256, 256, 0, stream>>>(sel_idx, sel_val, dinv,
                                                     out_val, col_cnt, col_pack);
    dense_row_kernel<<<ROWS, 256, 0, stream>>>(sel_idx, out_val, col_cnt,
                                               col_pack, diag2, out);
}